// Round 1
// baseline (271.244 us; speedup 1.0000x reference)
//
#include <hip/hip_runtime.h>
#include <hip/hip_bf16.h>
#include <stdint.h>

#define D_MODEL 1024
#define N_HEADS 16
#define N_KV 4
#define HD 64
#define BB 2
#define TT 1024
#define CACHE_LEN 1024
#define SS 2048
#define MAX_SEQ 4096
#define QKV_N 1536

typedef __attribute__((ext_vector_type(8))) short bf16x8;
typedef __attribute__((ext_vector_type(4))) float f32x4;

__device__ inline short f2bs(float f) {
    __hip_bfloat16 h = __float2bfloat16(f);
    return *reinterpret_cast<short*>(&h);
}

// ---------- x fp32 -> bf16 ----------
__global__ void k_convert_x(const float* __restrict__ x, short* __restrict__ xb, int n) {
    int i = (blockIdx.x * 256 + threadIdx.x) * 4;
    if (i < n) {
        float4 v = *reinterpret_cast<const float4*>(x + i);
        short4 o = make_short4(f2bs(v.x), f2bs(v.y), f2bs(v.z), f2bs(v.w));
        *reinterpret_cast<short4*>(xb + i) = o;
    }
}

// ---------- W [1024][N] fp32 -> Wt [N][1024] bf16 (tiled transpose) ----------
__global__ void k_transpose_w(const float* __restrict__ src, short* __restrict__ dst, int N) {
    __shared__ short tile[32][34];
    int tx = threadIdx.x & 31, ty = threadIdx.x >> 5; // ty 0..7
    int n0 = blockIdx.x * 32, k0 = blockIdx.y * 32;
#pragma unroll
    for (int i = 0; i < 4; i++) {
        int k = k0 + ty + i * 8;
        tile[ty + i * 8][tx] = f2bs(src[(size_t)k * N + n0 + tx]);
    }
    __syncthreads();
#pragma unroll
    for (int i = 0; i < 4; i++) {
        int n = n0 + ty + i * 8;
        dst[(size_t)n * 1024 + k0 + tx] = tile[tx][ty + i * 8];
    }
}

// ---------- C[M][N] fp32 = A[M][K]bf16 * Bt[N][K]bf16 ; 128x128 tile, BK=32 ----------
__global__ __launch_bounds__(256) void k_gemm_bt(
    const short* __restrict__ A, const short* __restrict__ Bt, float* __restrict__ C,
    int M, int N, int K) {
    __shared__ short sA[128 * 32];
    __shared__ short sB[128 * 32];
    int m0 = blockIdx.y * 128, n0 = blockIdx.x * 128;
    int g = threadIdx.x;
    int lane = g & 63, wave = g >> 6;
    int wr = wave >> 1, wc = wave & 1;
    int quad = lane >> 4, l15 = lane & 15;

    f32x4 acc[4][4] = {};

    for (int k0 = 0; k0 < K; k0 += 32) {
        __syncthreads();
#pragma unroll
        for (int it = 0; it < 2; it++) {
            int c = it * 256 + g;                 // 16B chunk index 0..511
            int row = c >> 2, col = (c & 3) << 3; // elem col
            const short* gpA = A + (size_t)(m0 + row) * K + k0 + col;
            const short* gpB = Bt + (size_t)(n0 + row) * K + k0 + col;
            int ub = (it * 256 + wave * 64) * 16; // wave-uniform LDS byte base
            __builtin_amdgcn_global_load_lds(
                (const __attribute__((address_space(1))) void*)gpA,
                (__attribute__((address_space(3))) void*)((char*)sA + ub), 16, 0, 0);
            __builtin_amdgcn_global_load_lds(
                (const __attribute__((address_space(1))) void*)gpB,
                (__attribute__((address_space(3))) void*)((char*)sB + ub), 16, 0, 0);
        }
        __syncthreads();
        bf16x8 af[4], bfr[4];
#pragma unroll
        for (int i = 0; i < 4; i++)
            af[i] = *reinterpret_cast<const bf16x8*>(sA + (wr * 64 + i * 16 + l15) * 32 + quad * 8);
#pragma unroll
        for (int j = 0; j < 4; j++)
            bfr[j] = *reinterpret_cast<const bf16x8*>(sB + (wc * 64 + j * 16 + l15) * 32 + quad * 8);
#pragma unroll
        for (int i = 0; i < 4; i++)
#pragma unroll
            for (int j = 0; j < 4; j++)
                acc[i][j] = __builtin_amdgcn_mfma_f32_16x16x32_bf16(af[i], bfr[j], acc[i][j], 0, 0, 0);
    }
#pragma unroll
    for (int i = 0; i < 4; i++) {
        int m = m0 + wr * 64 + i * 16 + quad * 4;
#pragma unroll
        for (int j = 0; j < 4; j++) {
            int n = n0 + wc * 64 + j * 16 + l15;
#pragma unroll
            for (int r = 0; r < 4; r++)
                C[(size_t)(m + r) * N + n] = acc[i][j][r];
        }
    }
}

// ---------- RoPE + scatter q/k/v ----------
__global__ void k_rope_assemble(const float* __restrict__ qkv, const int* __restrict__ pos,
                                short* __restrict__ qb, short* __restrict__ kb,
                                float* __restrict__ k_out, float* __restrict__ v_out) {
    int row = blockIdx.x; // b*1024 + t
    int b = row >> 10, t = row & 1023;
    int g = threadIdx.x;
    int idx = pos[b * TT + t] + t + CACHE_LEN;
    idx = min(max(idx, 0), MAX_SEQ - 1);
    float fidx = (float)idx;
    const float* src = qkv + (size_t)row * QKV_N;

    // q: 16 heads x 32 pairs, pre-scale by 1/sqrt(64)=0.125
#pragma unroll
    for (int p = g; p < 512; p += 256) {
        int h = p >> 5, i = p & 31;
        float inv = expf(-(float)i * (9.210340371976184f / 32.0f));
        float sv, cv;
        sincosf(fidx * inv, &sv, &cv);
        float x1 = src[h * 64 + i], x2 = src[h * 64 + i + 32];
        size_t qbase = ((size_t)(b * N_HEADS + h) * TT + t) * HD;
        qb[qbase + i]      = f2bs((x1 * cv - x2 * sv) * 0.125f);
        qb[qbase + i + 32] = f2bs((x2 * cv + x1 * sv) * 0.125f);
    }
    // k: 4 heads x 32 pairs
    if (g < 128) {
        int h = g >> 5, i = g & 31;
        float inv = expf(-(float)i * (9.210340371976184f / 32.0f));
        float sv, cv;
        sincosf(fidx * inv, &sv, &cv);
        float x1 = src[1024 + h * 64 + i], x2 = src[1024 + h * 64 + i + 32];
        float o1 = x1 * cv - x2 * sv;
        float o2 = x2 * cv + x1 * sv;
        size_t kbase = ((size_t)(b * N_KV + h) * SS + CACHE_LEN + t) * HD;
        k_out[kbase + i] = o1;
        k_out[kbase + i + 32] = o2;
        kb[kbase + i] = f2bs(o1);
        kb[kbase + i + 32] = f2bs(o2);
    }
    // v: 4 heads x 64 dims
    {
        int h = g >> 6, d = g & 63;
        float val = src[1280 + h * 64 + d];
        v_out[((size_t)(b * N_KV + h) * SS + CACHE_LEN + t) * HD + d] = val;
    }
}

// ---------- build vt bf16 [B][4][64][2048] (transposed V) ----------
__global__ void k_vt_build(const float* __restrict__ v_cache, const float* __restrict__ qkv,
                           short* __restrict__ vt) {
    __shared__ short tile[64][74];
    int blk = blockIdx.x;
    int st = blk & 31; // s-tile
    int bh = blk >> 5; // b*4+h
    int b = bh >> 2, h = bh & 3;
    int s0 = st * 64;
    int g = threadIdx.x;
#pragma unroll
    for (int i = 0; i < 16; i++) {
        int idx = i * 256 + g;
        int sl = idx >> 6, d = idx & 63;
        int s = s0 + sl;
        float val;
        if (s < CACHE_LEN)
            val = v_cache[((size_t)(bh)*CACHE_LEN + s) * HD + d];
        else
            val = qkv[(size_t)(b * TT + (s - CACHE_LEN)) * QKV_N + 1280 + h * 64 + d];
        tile[sl][d] = f2bs(val);
    }
    __syncthreads();
#pragma unroll
    for (int i = 0; i < 16; i++) {
        int idx = i * 256 + g;
        int d = idx >> 6, sl = idx & 63;
        vt[((size_t)bh * HD + d) * SS + s0 + sl] = tile[sl][d];
    }
}

// ---------- copy caches into fp32 outputs + kb bf16 ----------
__global__ void k_cache_copy(const float* __restrict__ k_cache, const float* __restrict__ v_cache,
                             float* __restrict__ k_out, float* __restrict__ v_out,
                             short* __restrict__ kb) {
    int i = blockIdx.x * 256 + threadIdx.x; // 0..524287
    int d = i & 63;
    int s = (i >> 6) & 1023;
    int bh = i >> 16;
    size_t oidx = ((size_t)bh * SS + s) * HD + d;
    float kv = k_cache[i];
    k_out[oidx] = kv;
    kb[oidx] = f2bs(kv);
    v_out[oidx] = v_cache[i];
}

// ---------- attention: block = (b,h, 64 q rows), 4 waves x 16 rows ----------
__global__ __launch_bounds__(256) void k_attn(
    const short* __restrict__ qb, const short* __restrict__ kb, const short* __restrict__ vt,
    short* __restrict__ ob) {
    int bh = blockIdx.x; // b*16 + h
    int b = bh >> 4, h = bh & 15;
    int hkv = h >> 2;
    int qt0 = blockIdx.y * 64;
    int g = threadIdx.x, lane = g & 63, wave = g >> 6;
    int quad = lane >> 4, l15 = lane & 15;
    int tw = qt0 + wave * 16;

    __shared__ short plds[4][16][72];

    const short* qrow = qb + ((size_t)bh * TT + tw + l15) * HD;
    bf16x8 aq0 = *reinterpret_cast<const bf16x8*>(qrow + quad * 8);
    bf16x8 aq1 = *reinterpret_cast<const bf16x8*>(qrow + 32 + quad * 8);

    const short* kbase = kb + (size_t)(b * N_KV + hkv) * SS * HD;
    const short* vbase = vt + (size_t)(b * N_KV + hkv) * HD * SS;

    f32x4 o[4] = {};
    float mr[4], lr[4];
#pragma unroll
    for (int r = 0; r < 4; r++) { mr[r] = -1e30f; lr[r] = 0.f; }

    for (int s0 = 0; s0 < SS; s0 += 64) {
        f32x4 sc[4] = {};
#pragma unroll
        for (int nt = 0; nt < 4; nt++) {
            const short* krow = kbase + (size_t)(s0 + nt * 16 + l15) * HD;
            bf16x8 bk0 = *reinterpret_cast<const bf16x8*>(krow + quad * 8);
            bf16x8 bk1 = *reinterpret_cast<const bf16x8*>(krow + 32 + quad * 8);
            sc[nt] = __builtin_amdgcn_mfma_f32_16x16x32_bf16(aq0, bk0, sc[nt], 0, 0, 0);
            sc[nt] = __builtin_amdgcn_mfma_f32_16x16x32_bf16(aq1, bk1, sc[nt], 0, 0, 0);
        }
#pragma unroll
        for (int r = 0; r < 4; r++) {
            float rm = fmaxf(fmaxf(sc[0][r], sc[1][r]), fmaxf(sc[2][r], sc[3][r]));
            rm = fmaxf(rm, __shfl_xor(rm, 1));
            rm = fmaxf(rm, __shfl_xor(rm, 2));
            rm = fmaxf(rm, __shfl_xor(rm, 4));
            rm = fmaxf(rm, __shfl_xor(rm, 8));
            float mnew = fmaxf(mr[r], rm);
            float alpha = __expf(mr[r] - mnew);
            float rs = 0.f;
#pragma unroll
            for (int nt = 0; nt < 4; nt++) {
                float p = __expf(sc[nt][r] - mnew);
                sc[nt][r] = p;
                rs += p;
            }
            rs += __shfl_xor(rs, 1);
            rs += __shfl_xor(rs, 2);
            rs += __shfl_xor(rs, 4);
            rs += __shfl_xor(rs, 8);
            lr[r] = lr[r] * alpha + rs;
            mr[r] = mnew;
#pragma unroll
            for (int dt = 0; dt < 4; dt++) o[dt][r] *= alpha;
        }
#pragma unroll
        for (int nt = 0; nt < 4; nt++)
#pragma unroll
            for (int r = 0; r < 4; r++)
                plds[wave][quad * 4 + r][nt * 16 + l15] = f2bs(sc[nt][r]);
        // per-wave LDS buffer: in-wave DS ordering suffices, no barrier
        bf16x8 ap0 = *reinterpret_cast<const bf16x8*>(&plds[wave][l15][quad * 8]);
        bf16x8 ap1 = *reinterpret_cast<const bf16x8*>(&plds[wave][l15][32 + quad * 8]);
#pragma unroll
        for (int dt = 0; dt < 4; dt++) {
            const short* vrow = vbase + (size_t)(dt * 16 + l15) * SS + s0;
            bf16x8 bv0 = *reinterpret_cast<const bf16x8*>(vrow + quad * 8);
            bf16x8 bv1 = *reinterpret_cast<const bf16x8*>(vrow + 32 + quad * 8);
            o[dt] = __builtin_amdgcn_mfma_f32_16x16x32_bf16(ap0, bv0, o[dt], 0, 0, 0);
            o[dt] = __builtin_amdgcn_mfma_f32_16x16x32_bf16(ap1, bv1, o[dt], 0, 0, 0);
        }
    }
#pragma unroll
    for (int r = 0; r < 4; r++) {
        float inv = 1.0f / lr[r];
        int trow = b * TT + tw + quad * 4 + r;
#pragma unroll
        for (int dt = 0; dt < 4; dt++)
            ob[(size_t)trow * D_MODEL + h * HD + dt * 16 + l15] = f2bs(o[dt][r] * inv);
    }
}

extern "C" void kernel_launch(void* const* d_in, const int* in_sizes, int n_in,
                              void* d_out, int out_size, void* d_ws, size_t ws_size,
                              hipStream_t stream) {
    (void)in_sizes; (void)n_in; (void)out_size; (void)ws_size;
    const float* x       = (const float*)d_in[0];
    const float* k_cache = (const float*)d_in[1];
    const float* v_cache = (const float*)d_in[2];
    const int*   pos     = (const int*)d_in[3];
    const float* Wq      = (const float*)d_in[4];
    const float* Wk      = (const float*)d_in[5];
    const float* Wv      = (const float*)d_in[6];
    const float* Wo      = (const float*)d_in[7];

    float* out   = (float*)d_out;
    float* k_out = out + (size_t)BB * TT * D_MODEL;      // 2,097,152
    float* v_out = k_out + (size_t)BB * N_KV * SS * HD;  // +1,048,576

    char* ws = (char*)d_ws;
    short* xb   = (short*)(ws);               // 4 MB
    short* Wt   = (short*)(ws + (4u << 20));  // 3 MB  [1536][1024]
    short* Wot  = (short*)(ws + (7u << 20));  // 2 MB  [1024][1024]
    float* qkv  = (float*)(ws + (9u << 20));  // 12 MB [2048][1536]
    short* qbuf = (short*)(ws + (21u << 20)); // 4 MB  [B,H,T,64]
    short* kbuf = (short*)(ws + (25u << 20)); // 2 MB  [B,4,2048,64]
    short* vtb  = (short*)(ws + (27u << 20)); // 2 MB  [B,4,64,2048]
    short* obuf = (short*)(ws + (29u << 20)); // 4 MB  [2048][1024]

    k_convert_x<<<2048, 256, 0, stream>>>(x, xb, BB * TT * D_MODEL);
    k_transpose_w<<<dim3(32, 32), 256, 0, stream>>>(Wq, Wt, 1024);
    k_transpose_w<<<dim3(8, 32), 256, 0, stream>>>(Wk, Wt + (size_t)1024 * 1024, 256);
    k_transpose_w<<<dim3(8, 32), 256, 0, stream>>>(Wv, Wt + (size_t)1280 * 1024, 256);
    k_transpose_w<<<dim3(32, 32), 256, 0, stream>>>(Wo, Wot, 1024);

    k_gemm_bt<<<dim3(QKV_N / 128, 16), 256, 0, stream>>>(xb, Wt, qkv, 2048, QKV_N, 1024);

    k_rope_assemble<<<2048, 256, 0, stream>>>(qkv, pos, qbuf, kbuf, k_out, v_out);
    k_vt_build<<<256, 256, 0, stream>>>(v_cache, qkv, vtb);
    k_cache_copy<<<2048, 256, 0, stream>>>(k_cache, v_cache, k_out, v_out, kbuf);

    k_attn<<<dim3(BB * N_HEADS, TT / 64), 256, 0, stream>>>(qbuf, kbuf, vtb, obuf);

    k_gemm_bt<<<dim3(1024 / 128, 16), 256, 0, stream>>>(obuf, Wot, (float*)d_out, 2048, 1024, 1024);
}